// Round 10
// baseline (546.642 us; speedup 1.0000x reference)
//
#include <hip/hip_runtime.h>
#include <hip/hip_bf16.h>

// MicroContinuumCell — MI355X. f32 I/O; bf16 MFMA internally.
// v10: fused skeleton (r9) + x cross-subtile register prefetch + coalesced
// v_out via LDS vs-buffer + fragment-ordered parts (no RMW anywhere).
// Workspace (~203 MB): offsets in kernel_launch.

#define NTOK 262144

typedef short s16x4 __attribute__((ext_vector_type(4)));
typedef short s16x8 __attribute__((ext_vector_type(8)));
typedef float f32x4 __attribute__((ext_vector_type(4)));
typedef unsigned int u32x4 __attribute__((ext_vector_type(4)));
typedef __bf16 bf16x8 __attribute__((ext_vector_type(8)));

static __device__ __forceinline__ float b2f(short s) {
  unsigned int u = ((unsigned int)(unsigned short)s) << 16;
  return __builtin_bit_cast(float, u);
}
static __device__ __forceinline__ short f2b(float f) {
  __hip_bfloat16 h = __float2bfloat16(f);
  return (short)__builtin_bit_cast(unsigned short, h);
}
static __device__ __forceinline__ float clip2(float f) {
  return fminf(2.f, fmaxf(-2.f, f));
}
static __device__ __forceinline__ unsigned int packu(short lo, short hi) {
  return (unsigned int)(unsigned short)lo | ((unsigned int)(unsigned short)hi << 16);
}
static __device__ __forceinline__ f32x4 mfma16(s16x8 a, s16x8 b, f32x4 c) {
  return __builtin_amdgcn_mfma_f32_16x16x32_bf16(
      __builtin_bit_cast(bf16x8, a), __builtin_bit_cast(bf16x8, b), c, 0, 0, 0);
}

// ---------------------------------------------------------------- k_prep
__global__ __launch_bounds__(1024) void k_prep(const float* __restrict__ V,
                                               const float* __restrict__ W,
                                               short* __restrict__ Vb,
                                               short* __restrict__ Wb,
                                               float* __restrict__ scal) {
  int t = blockIdx.x * 1024 + threadIdx.x;
  f32x4 v4 = *(const f32x4*)(V + (size_t)t * 4);
  f32x4 w4 = *(const f32x4*)(W + (size_t)t * 4);
  s16x4 vb, wb;
  float s = 0.f;
#pragma unroll
  for (int e = 0; e < 4; ++e) {
    vb[e] = f2b(v4[e]);
    wb[e] = f2b(w4[e]);
    s += w4[e] * w4[e];
  }
  *(s16x4*)(Vb + (size_t)t * 4) = vb;
  *(s16x4*)(Wb + (size_t)t * 4) = wb;
#pragma unroll
  for (int d = 1; d < 64; d <<= 1) s += __shfl_xor(s, d);
  __shared__ float r[16];
  if ((threadIdx.x & 63) == 0) r[threadIdx.x >> 6] = s;
  __syncthreads();
  if (threadIdx.x == 0) {
    float tt = 0.f;
#pragma unroll
    for (int i = 0; i < 16; ++i) tt += r[i];
    atomicAdd(&scal[0], tt);
  }
}

// ---------------------------------------------------------------- k_fused
// 256 blocks x 512 threads; 1024 rows/block; 32 sub-tiles of 32 rows.
// S: convert prefetched regs -> xs,xT + row stats | G: issue x(nt+1) loads,
// v/h MFMA (B from L2), stats, vT + vs writes | H: coalesced vs->v_out copy,
// hebb MFMA. Epilogue: fragment-ordered parts, colv2, per-row MLP, scal.
__global__ __launch_bounds__(512) void k_fused(
    const float* __restrict__ x, const short* __restrict__ Vb,
    const short* __restrict__ Wb, const float* __restrict__ gw,
    const float* __restrict__ gb, const float* __restrict__ s1w,
    const float* __restrict__ s1b, const float* __restrict__ lng,
    const float* __restrict__ lnb, const float* __restrict__ s2w,
    const float* __restrict__ s2b, const float* __restrict__ aw,
    const float* __restrict__ ab, short* __restrict__ v_out,
    float* __restrict__ g_out, float* __restrict__ scal,
    float* __restrict__ colv2, float* __restrict__ parts) {
  __shared__ __align__(16) short xs[32 * 264];         // 16.5 KiB
  __shared__ __align__(16) short vs[32 * 264];         // 16.5 KiB
  __shared__ __align__(16) unsigned int xT[256 * 17];  // 17 KiB
  __shared__ __align__(16) unsigned int vT[256 * 17];  // 17 KiB
  __shared__ float stat[4096];  // [0)gate [1024)|h| [2048)sx [3072)sxx
  int tid = threadIdx.x;
  int lane = tid & 63, wid = tid >> 6;
  int lr = lane & 15, lg = lane >> 4;
  int wr = wid >> 2, wc = wid & 3;                // hebb 2x4 wave grid
  int np = tid >> 5, ic = tid & 31, i0 = ic * 8;  // staging roles
  int c0 = wid * 32;                              // v/h col group per wave
  size_t n0 = (size_t)blockIdx.x * 1024;

  f32x4 hb[8][4] = {};  // hebb accumulator (persists in AGPRs)
  float cv2[2] = {0.f, 0.f};

#pragma unroll
  for (int q = 0; q < 4; ++q) stat[q * 512 + tid] = 0.f;

  // prefetch registers (subtile nt: rows 2np, 2np+1; 32B each)
  f32x4 rxa0, rxa1, rxb0, rxb1;
  {
    const float* pa = x + (n0 + 2 * np) * 256 + i0;
    rxa0 = *(const f32x4*)pa;
    rxa1 = *(const f32x4*)(pa + 4);
    rxb0 = *(const f32x4*)(pa + 256);
    rxb1 = *(const f32x4*)(pa + 260);
  }

  for (int nt = 0; nt < 32; ++nt) {
    int rbase = nt * 32;
    // ---------------- Phase S: convert prefetched regs -> xs, xT, stats
    {
      s16x8 ca, cb;
      float sA = 0.f, qA = 0.f, sB = 0.f, qB = 0.f;
#pragma unroll
      for (int j = 0; j < 4; ++j) {
        sA += rxa0[j] + rxa1[j];
        qA += rxa0[j] * rxa0[j] + rxa1[j] * rxa1[j];
        sB += rxb0[j] + rxb1[j];
        qB += rxb0[j] * rxb0[j] + rxb1[j] * rxb1[j];
        ca[j] = f2b(rxa0[j]); ca[4 + j] = f2b(rxa1[j]);
        cb[j] = f2b(rxb0[j]); cb[4 + j] = f2b(rxb1[j]);
      }
      *(s16x8*)(xs + (2 * np) * 264 + i0) = ca;
      *(s16x8*)(xs + (2 * np + 1) * 264 + i0) = cb;
#pragma unroll
      for (int j = 0; j < 4; ++j) {
        xT[(i0 + j) * 17 + np] = packu(ca[j], cb[j]);
        xT[(i0 + 4 + j) * 17 + np] = packu(ca[4 + j], cb[4 + j]);
      }
#pragma unroll
      for (int d = 1; d < 32; d <<= 1) {
        sA += __shfl_xor(sA, d); qA += __shfl_xor(qA, d);
        sB += __shfl_xor(sB, d); qB += __shfl_xor(qB, d);
      }
      if (ic == 0) {
        stat[2048 + rbase + 2 * np] = sA;
        stat[3072 + rbase + 2 * np] = qA;
        stat[2048 + rbase + 2 * np + 1] = sB;
        stat[3072 + rbase + 2 * np + 1] = qB;
      }
    }
    __syncthreads();
    // ---------------- Phase G: issue next subtile's x loads FIRST
    if (nt < 31) {
      const float* pa = x + (n0 + (nt + 1) * 32 + 2 * np) * 256 + i0;
      rxa0 = *(const f32x4*)pa;
      rxa1 = *(const f32x4*)(pa + 4);
      rxb0 = *(const f32x4*)(pa + 256);
      rxb1 = *(const f32x4*)(pa + 260);
    }
    // v & h GEMM (wave's 32 cols), stats, vT + vs
    f32x4 av[2][2] = {}, ah[2][2] = {};
#pragma unroll
    for (int ks = 0; ks < 8; ++ks) {
      int kb = ks * 32 + lg * 8;
      s16x8 A0 = *(const s16x8*)(xs + lr * 264 + kb);
      s16x8 A1 = *(const s16x8*)(xs + (16 + lr) * 264 + kb);
      s16x8 bv0 = *(const s16x8*)(Vb + (size_t)(c0 + lr) * 256 + kb);
      s16x8 bv1 = *(const s16x8*)(Vb + (size_t)(c0 + 16 + lr) * 256 + kb);
      s16x8 bw0 = *(const s16x8*)(Wb + (size_t)(c0 + lr) * 256 + kb);
      s16x8 bw1 = *(const s16x8*)(Wb + (size_t)(c0 + 16 + lr) * 256 + kb);
      av[0][0] = mfma16(A0, bv0, av[0][0]);
      av[0][1] = mfma16(A0, bv1, av[0][1]);
      av[1][0] = mfma16(A1, bv0, av[1][0]);
      av[1][1] = mfma16(A1, bv1, av[1][1]);
      ah[0][0] = mfma16(A0, bw0, ah[0][0]);
      ah[0][1] = mfma16(A0, bw1, ah[0][1]);
      ah[1][0] = mfma16(A1, bw0, ah[1][0]);
      ah[1][1] = mfma16(A1, bw1, ah[1][1]);
    }
    {
      float gw0 = gw[c0 + lr], gw1 = gw[c0 + 16 + lr];
#pragma unroll
      for (int mf = 0; mf < 2; ++mf)
#pragma unroll
        for (int e = 0; e < 4; ++e) {
          float v0 = clip2(av[mf][0][e]), v1 = clip2(av[mf][1][e]);
          av[mf][0][e] = v0; av[mf][1][e] = v1;
          cv2[0] += v0 * v0; cv2[1] += v1 * v1;
          float gd = v0 * gw0 + v1 * gw1;
          float hs = fabsf(ah[mf][0][e]) + fabsf(ah[mf][1][e]);
#pragma unroll
          for (int d = 1; d < 16; d <<= 1) {
            gd += __shfl_xor(gd, d);
            hs += __shfl_xor(hs, d);
          }
          if (lr == 0) {
            int row = rbase + mf * 16 + lg * 4 + e;
            atomicAdd(&stat[row], gd);
            atomicAdd(&stat[1024 + row], hs);
          }
        }
      // vs (row-major bf16) + vT (pair-packed transposed)
#pragma unroll
      for (int mf = 0; mf < 2; ++mf)
#pragma unroll
        for (int nf = 0; nf < 2; ++nf) {
          int col = c0 + nf * 16 + lr;
#pragma unroll
          for (int e = 0; e < 4; ++e) {
            int row = mf * 16 + lg * 4 + e;
            vs[row * 264 + col] = f2b(av[mf][nf][e]);
          }
          int npb2 = mf * 8 + lg * 2;
          vT[col * 17 + npb2] = packu(f2b(av[mf][nf][0]), f2b(av[mf][nf][1]));
          vT[col * 17 + npb2 + 1] =
              packu(f2b(av[mf][nf][2]), f2b(av[mf][nf][3]));
        }
    }
    __syncthreads();
    // ---------------- Phase H: coalesced v copy + hebb MFMA
    {
#pragma unroll
      for (int q = 0; q < 2; ++q) {
        int item = q * 512 + tid;  // 0..1023 = 32 rows x 32 chunks(16B)
        int row = item >> 5, c8 = item & 31;
        *(s16x8*)(v_out + (n0 + rbase + row) * 256 + c8 * 8) =
            *(const s16x8*)(vs + row * 264 + c8 * 8);
      }
      int npb = lg * 4;
      s16x8 bfr[4];
#pragma unroll
      for (int nf = 0; nf < 4; ++nf) {
        int j = wc * 64 + nf * 16 + lr;
        u32x4 q;
        q[0] = xT[j * 17 + npb]; q[1] = xT[j * 17 + npb + 1];
        q[2] = xT[j * 17 + npb + 2]; q[3] = xT[j * 17 + npb + 3];
        bfr[nf] = __builtin_bit_cast(s16x8, q);
      }
#pragma unroll
      for (int mf = 0; mf < 8; ++mf) {
        int i = wr * 128 + mf * 16 + lr;
        u32x4 q;
        q[0] = vT[i * 17 + npb]; q[1] = vT[i * 17 + npb + 1];
        q[2] = vT[i * 17 + npb + 2]; q[3] = vT[i * 17 + npb + 3];
        s16x8 afr = __builtin_bit_cast(s16x8, q);
#pragma unroll
        for (int nf = 0; nf < 4; ++nf)
          hb[mf][nf] = mfma16(afr, bfr[nf], hb[mf][nf]);
      }
    }
    __syncthreads();
  }

  // ---------------- block epilogue
  // parts: fragment-ordered, each thread's f32x4 contiguous (coalesced 16B)
  float* myp = parts + (size_t)blockIdx.x * 65536;
#pragma unroll
  for (int mf = 0; mf < 8; ++mf)
#pragma unroll
    for (int nf = 0; nf < 4; ++nf) {
      float* dst = myp + (size_t)(((wid * 8 + mf) * 4 + nf) * 64 + lane) * 4;
      *(f32x4*)dst = hb[mf][nf];
    }
  cv2[0] += __shfl_xor(cv2[0], 16); cv2[0] += __shfl_xor(cv2[0], 32);
  cv2[1] += __shfl_xor(cv2[1], 16); cv2[1] += __shfl_xor(cv2[1], 32);
  if (lg == 0) {
    atomicAdd(&colv2[c0 + lr], cv2[0]);
    atomicAdd(&colv2[c0 + 16 + lr], cv2[1]);
  }
  // deferred per-row MLP: 2 rows/thread
  float c0s = 0.f, c2s = 0.f;
  float wnorm = sqrtf(scal[0]);
#pragma unroll
  for (int rr = 0; rr < 2; ++rr) {
    int r = tid + rr * 512;
    float mean = stat[2048 + r] * (1.f / 256.f);
    float var = stat[3072 + r] * (1.f / 256.f) - mean * mean;
    float st[4];
    st[0] = fabsf(var - 0.5f);
    st[1] = stat[1024 + r] * (1.f / 256.f);
    st[2] = wnorm;
    st[3] = 0.5f;
    float z[16];
#pragma unroll
    for (int o = 0; o < 16; ++o) {
      float a = s1b[o];
#pragma unroll
      for (int i = 0; i < 4; ++i) a += s1w[o * 4 + i] * st[i];
      z[o] = a;
    }
    float mu = 0.f;
#pragma unroll
    for (int o = 0; o < 16; ++o) mu += z[o];
    mu *= (1.f / 16.f);
    float vz = 0.f;
#pragma unroll
    for (int o = 0; o < 16; ++o) { float d2 = z[o] - mu; vz += d2 * d2; }
    vz *= (1.f / 16.f);
    float rs = rsqrtf(vz + 1e-5f);
#pragma unroll
    for (int o = 0; o < 16; ++o)
      z[o] = tanhf((z[o] - mu) * rs * lng[o] + lnb[o]);
    float z2[8];
#pragma unroll
    for (int o = 0; o < 8; ++o) {
      float a = s2b[o];
#pragma unroll
      for (int i = 0; i < 16; ++i) a += s2w[o * 16 + i] * z[i];
      z2[o] = fmaxf(a, 0.f);
    }
#pragma unroll
    for (int q = 0; q < 2; ++q) {
      int o = q * 2;
      float a = ab[o];
#pragma unroll
      for (int i = 0; i < 8; ++i) a += aw[o * 8 + i] * z2[i];
      float cc = 1.f / (1.f + expf(-a));
      if (q == 0) c0s += cc; else c2s += cc;
    }
    g_out[n0 + r] = 1.f / (1.f + expf(-(stat[r] + gb[0])));
  }
#pragma unroll
  for (int d = 1; d < 64; d <<= 1) {
    c0s += __shfl_xor(c0s, d);
    c2s += __shfl_xor(c2s, d);
  }
  __syncthreads();  // xT dead; reuse as scratch
  float* rsum = (float*)xT;
  if (lane == 0) { rsum[wid] = c0s; rsum[8 + wid] = c2s; }
  __syncthreads();
  if (tid == 0) {
    float a = 0.f, b = 0.f;
#pragma unroll
    for (int i = 0; i < 8; ++i) { a += rsum[i]; b += rsum[8 + i]; }
    atomicAdd(&scal[1], a);
    atomicAdd(&scal[2], b);
  }
}

// ---------------------------------------------------------------- k_mem1
// Reads fragment-ordered parts coalesced. 256 blocks x 64 threads; each
// thread owns (ibase = bid>>2, j = (bid&3)*64+tid) -> 4 rows via e.
__global__ __launch_bounds__(64) void k_mem1(
    const float* __restrict__ parts, const float* __restrict__ colv2,
    const float* __restrict__ sm, float* __restrict__ mem,
    float* __restrict__ scal) {
  int tid = threadIdx.x, bid = blockIdx.x;
  int ibase = bid >> 2;                // 0..63  (i = ibase*4 + e)
  int j = (bid & 3) * 64 + tid;        // 0..255
  int wr = ibase >> 5, mf = (ibase >> 2) & 7, lg = ibase & 3;
  int wc = j >> 6, nf = (j >> 4) & 3, lr = j & 15;
  int flat = (((wr * 4 + wc) * 8 + mf) * 4 + nf) * 64 + lg * 16 + lr;
  const float* src = parts + (size_t)flat * 4;
  f32x4 acc = {0.f, 0.f, 0.f, 0.f};
#pragma unroll 4
  for (int p = 0; p < 256; ++p) {
    f32x4 v = *(const f32x4*)(src + (size_t)p * 65536);
    acc += v;
  }
  float mr = scal[1] * (1.f / 262144.f);  // metabolic_rate
  float s = 0.f;
#pragma unroll
  for (int e = 0; e < 4; ++e) {
    int i = ibase * 4 + e;
    float hebb = acc[e] * (1.f / 262144.f);
    float smv = sm[i * 256 + j];
    float forget = colv2[i] * (1.f / 262144.f) * smv;
    float m = smv + tanhf(hebb - forget) * mr * 0.1f;
    mem[i * 256 + j] = m;
    s += m * m;
  }
#pragma unroll
  for (int d = 1; d < 64; d <<= 1) s += __shfl_xor(s, d);
  if (tid == 0) atomicAdd(&scal[3], s);
}

__global__ __launch_bounds__(256) void k_mem2(const float* __restrict__ mem,
                                              const float* __restrict__ scal,
                                              float* __restrict__ out1) {
  int idx = blockIdx.x * 256 + threadIdx.x;
  float scale = 0.5f / fmaxf(sqrtf(scal[3]), 1e-6f);
  out1[idx] = mem[idx] * scale;
}

// ---------------------------------------------------------------- k_out
__global__ __launch_bounds__(256) void k_out(const short* __restrict__ v_in,
                                             const float* __restrict__ g_sig,
                                             const float* __restrict__ scal,
                                             float* __restrict__ out0) {
  size_t t = (size_t)blockIdx.x * 256 + threadIdx.x;
  float gv = scal[2] * (1.f / 262144.f);
  size_t n = t >> 5;
  int off = (int)(t & 31) * 8;
  float s = g_sig[n] * gv;
  s16x8 v8 = *(const s16x8*)(v_in + n * 256 + off);
  f32x4 o0, o1;
#pragma unroll
  for (int j = 0; j < 4; ++j) {
    o0[j] = clip2(b2f(v8[j]) * s);
    o1[j] = clip2(b2f(v8[4 + j]) * s);
  }
  *(f32x4*)(out0 + n * 256 + off) = o0;
  *(f32x4*)(out0 + n * 256 + off + 4) = o1;
}

// ---------------------------------------------------------------- launch
extern "C" void kernel_launch(void* const* d_in, const int* in_sizes, int n_in,
                              void* d_out, int out_size, void* d_ws, size_t ws_size,
                              hipStream_t stream) {
  (void)in_sizes; (void)n_in; (void)out_size; (void)ws_size;
  const float* x   = (const float*)d_in[0];
  const float* Wm  = (const float*)d_in[1];
  const float* Vm  = (const float*)d_in[2];
  const float* gw  = (const float*)d_in[3];
  const float* gb  = (const float*)d_in[4];
  const float* s1w = (const float*)d_in[5];
  const float* s1b = (const float*)d_in[6];
  const float* lng = (const float*)d_in[7];
  const float* lnb = (const float*)d_in[8];
  const float* s2w = (const float*)d_in[9];
  const float* s2b = (const float*)d_in[10];
  const float* aw  = (const float*)d_in[11];
  const float* ab  = (const float*)d_in[12];
  const float* sm  = (const float*)d_in[13];
  float* out0 = (float*)d_out;
  float* out1 = out0 + (size_t)NTOK * 256;

  char* w = (char*)d_ws;
  short* v_ws  = (short*)w;                    // 134217728
  float* g_ws  = (float*)(w + 134217728);      // 1048576
  float* scal  = (float*)(w + 135266304);      // 256
  float* colv2 = (float*)(w + 135266560);      // 1024
  float* mem   = (float*)(w + 135267584);      // 262144
  float* parts = (float*)(w + 135529728);      // 67108864
  short* Vb    = (short*)(w + 202638592);      // 131072
  short* Wb    = (short*)(w + 202769664);      // 131072

  hipMemsetAsync(scal, 0, 1280, stream);       // scal[64] + colv2[256]
  k_prep<<<16, 1024, 0, stream>>>(Vm, Wm, Vb, Wb, scal);
  k_fused<<<256, 512, 0, stream>>>(x, Vb, Wb, gw, gb, s1w, s1b, lng, lnb,
                                   s2w, s2b, aw, ab, v_ws, g_ws, scal,
                                   colv2, parts);
  k_mem1<<<256, 64, 0, stream>>>(parts, colv2, sm, mem, scal);
  k_mem2<<<256, 256, 0, stream>>>(mem, scal, out1);
  k_out<<<32768, 256, 0, stream>>>(v_ws, g_ws, scal, out0);
}

// Round 11
// 425.158 us; speedup vs baseline: 1.2857x; 1.2857x over previous
//
#include <hip/hip_runtime.h>
#include <hip/hip_bf16.h>

// MicroContinuumCell — MI355X. f32 I/O; bf16 MFMA internally.
// v11 = r5 (best measured, 400us) + coalesced v_out via LDS bounce (k_main)
//     + fragment-ordered coalesced parts (k_hebb) + matching k_mem1.
// Workspace (~203 MB): offsets in kernel_launch.

#define NTOK 262144

typedef short s16x4 __attribute__((ext_vector_type(4)));
typedef short s16x8 __attribute__((ext_vector_type(8)));
typedef float f32x4 __attribute__((ext_vector_type(4)));
typedef unsigned int u32x4 __attribute__((ext_vector_type(4)));
typedef __bf16 bf16x8 __attribute__((ext_vector_type(8)));

static __device__ __forceinline__ float b2f(short s) {
  unsigned int u = ((unsigned int)(unsigned short)s) << 16;
  return __builtin_bit_cast(float, u);
}
static __device__ __forceinline__ short f2b(float f) {
  __hip_bfloat16 h = __float2bfloat16(f);
  return (short)__builtin_bit_cast(unsigned short, h);
}
static __device__ __forceinline__ float clip2(float f) {
  return fminf(2.f, fmaxf(-2.f, f));
}
static __device__ __forceinline__ unsigned int packu(short lo, short hi) {
  return (unsigned int)(unsigned short)lo | ((unsigned int)(unsigned short)hi << 16);
}
static __device__ __forceinline__ f32x4 mfma16(s16x8 a, s16x8 b, f32x4 c) {
  return __builtin_amdgcn_mfma_f32_16x16x32_bf16(
      __builtin_bit_cast(bf16x8, a), __builtin_bit_cast(bf16x8, b), c, 0, 0, 0);
}

// ---------------------------------------------------------------- k_prep
__global__ __launch_bounds__(1024) void k_prep(const float* __restrict__ V,
                                               const float* __restrict__ W,
                                               short* __restrict__ Vb,
                                               short* __restrict__ Wb,
                                               float* __restrict__ scal) {
  int t = blockIdx.x * 1024 + threadIdx.x;
  f32x4 v4 = *(const f32x4*)(V + (size_t)t * 4);
  f32x4 w4 = *(const f32x4*)(W + (size_t)t * 4);
  s16x4 vb, wb;
  float s = 0.f;
#pragma unroll
  for (int e = 0; e < 4; ++e) {
    vb[e] = f2b(v4[e]);
    wb[e] = f2b(w4[e]);
    s += w4[e] * w4[e];
  }
  *(s16x4*)(Vb + (size_t)t * 4) = vb;
  *(s16x4*)(Wb + (size_t)t * 4) = wb;
#pragma unroll
  for (int d = 1; d < 64; d <<= 1) s += __shfl_xor(s, d);
  __shared__ float r[16];
  if ((threadIdx.x & 63) == 0) r[threadIdx.x >> 6] = s;
  __syncthreads();
  if (threadIdx.x == 0) {
    float tt = 0.f;
#pragma unroll
    for (int i = 0; i < 16; ++i) tt += r[i];
    atomicAdd(&scal[0], tt);
  }
}

// ---------------------------------------------------------------- k_main
// r5 structure: 64 rows/block, 8 waves product-split (mat = wid>>2,
// wc = wid&3), BK=32, x via LDS + 1-deep register prefetch, B direct L2.
// NEW: clipped v bounced through LDS (vs2) -> coalesced 16B stores.
__global__ __launch_bounds__(512) void k_main(
    const float* __restrict__ x, const short* __restrict__ Vb,
    const short* __restrict__ Wb, const float* __restrict__ gw,
    const float* __restrict__ gb, const float* __restrict__ s1w,
    const float* __restrict__ s1b, const float* __restrict__ lng,
    const float* __restrict__ lnb, const float* __restrict__ s2w,
    const float* __restrict__ s2b, const float* __restrict__ aw,
    const float* __restrict__ ab, short* __restrict__ v_out,
    float* __restrict__ g_out, float* __restrict__ scal) {
  __shared__ __align__(16) short xs[64 * 40];    // 5 KiB
  __shared__ __align__(16) short vs2[64 * 264];  // 33 KiB bounce for v
  __shared__ float red[256];
  int tid = threadIdx.x;
  int lane = tid & 63, wid = tid >> 6;
  int lr = lane & 15, lg = lane >> 4;
  int mat = wid >> 2, wc = wid & 3;
  size_t r0 = (size_t)blockIdx.x * 64;

  f32x4 acc[4][4] = {};
  float sx = 0.f, sxx = 0.f;
  int srow = tid >> 3, skc = tid & 7;  // staging: row 0..63, 4-float chunk

  const short* Bm = mat ? Wb : Vb;
  const short* bbase = Bm + (size_t)(wc * 64 + lr) * 256 + lg * 8;
  const float* xsrc = x + (r0 + srow) * 256 + skc * 4;

  // prologue: prefetch ks=0
  f32x4 rx = *(const f32x4*)(xsrc);
  s16x8 bcur[4], bnext[4];
#pragma unroll
  for (int nf = 0; nf < 4; ++nf)
    bcur[nf] = *(const s16x8*)(bbase + nf * 16 * 256);

#pragma unroll
  for (int ks = 0; ks < 8; ++ks) {
    // ---- stats + convert + LDS write of current x chunk
    {
      s16x4 c;
#pragma unroll
      for (int e = 0; e < 4; ++e) {
        float f = rx[e];
        sx += f;
        sxx += f * f;
        c[e] = f2b(f);
      }
      *(s16x4*)(xs + srow * 40 + skc * 4) = c;
    }
    __syncthreads();
    // ---- issue next K-step's loads (hide under ds_read + MFMA)
    if (ks < 7) {
      rx = *(const f32x4*)(xsrc + (ks + 1) * 32);
#pragma unroll
      for (int nf = 0; nf < 4; ++nf)
        bnext[nf] = *(const s16x8*)(bbase + nf * 16 * 256 + (ks + 1) * 32);
    }
    // ---- A fragments from LDS + MFMA (uses prefetched bcur)
#pragma unroll
    for (int mf = 0; mf < 4; ++mf) {
      s16x8 a = *(const s16x8*)(xs + (mf * 16 + lr) * 40 + lg * 8);
#pragma unroll
      for (int nf = 0; nf < 4; ++nf)
        acc[mf][nf] = mfma16(a, bcur[nf], acc[mf][nf]);
    }
    __syncthreads();
#pragma unroll
    for (int nf = 0; nf < 4; ++nf) bcur[nf] = bnext[nf];
  }

  // per-lane partials per output row: V-waves gate-dot, W-waves sum|h|
  float pl[4][4];
  if (mat == 0) {
    float gw4[4];
#pragma unroll
    for (int nf = 0; nf < 4; ++nf) gw4[nf] = gw[wc * 64 + nf * 16 + lr];
#pragma unroll
    for (int mf = 0; mf < 4; ++mf)
#pragma unroll
      for (int e = 0; e < 4; ++e) {
        float g = 0.f;
#pragma unroll
        for (int nf = 0; nf < 4; ++nf) {
          float v = clip2(acc[mf][nf][e]);
          acc[mf][nf][e] = v;
          g += v * gw4[nf];
        }
        pl[mf][e] = g;
      }
  } else {
#pragma unroll
    for (int mf = 0; mf < 4; ++mf)
#pragma unroll
      for (int e = 0; e < 4; ++e) {
        float hbs = 0.f;
#pragma unroll
        for (int nf = 0; nf < 4; ++nf) hbs += fabsf(acc[mf][nf][e]);
        pl[mf][e] = hbs;
      }
  }
  // butterfly over the 16-col lane group (C/D: col = lane&15)
#pragma unroll
  for (int d = 1; d < 16; d <<= 1)
#pragma unroll
    for (int mf = 0; mf < 4; ++mf)
#pragma unroll
      for (int e = 0; e < 4; ++e) pl[mf][e] += __shfl_xor(pl[mf][e], d);
  // row-stat reduce over the 8 threads sharing a staging row
  sx += __shfl_xor(sx, 1); sx += __shfl_xor(sx, 2); sx += __shfl_xor(sx, 4);
  sxx += __shfl_xor(sxx, 1); sxx += __shfl_xor(sxx, 2); sxx += __shfl_xor(sxx, 4);

  if (tid < 128) red[tid] = 0.f;
  __syncthreads();
  if (lr == 0) {
#pragma unroll
    for (int mf = 0; mf < 4; ++mf)
#pragma unroll
      for (int e = 0; e < 4; ++e) {
        int row = mf * 16 + lg * 4 + e;
        atomicAdd(&red[mat * 64 + row], pl[mf][e]);
      }
  }
  if ((tid & 7) == 0) { red[64 + 64 + srow] = sx; red[192 + srow] = sxx; }
  // clipped v -> LDS bounce (cheap 2B LDS scatter; V-waves only)
  if (mat == 0) {
#pragma unroll
    for (int mf = 0; mf < 4; ++mf)
#pragma unroll
      for (int nf = 0; nf < 4; ++nf)
#pragma unroll
        for (int e = 0; e < 4; ++e) {
          int row = mf * 16 + lg * 4 + e;
          int col = wc * 64 + nf * 16 + lr;
          vs2[row * 264 + col] = f2b(acc[mf][nf][e]);
        }
  }
  __syncthreads();
  // coalesced v_out copy: 64 rows x 32 chunks(16B) = 2048 items
#pragma unroll
  for (int q = 0; q < 4; ++q) {
    int item = q * 512 + tid;
    int row = item >> 5, c8 = item & 31;
    *(s16x8*)(v_out + (r0 + row) * 256 + c8 * 8) =
        *(const s16x8*)(vs2 + row * 264 + c8 * 8);
  }

  // homeostatic MLP: one thread per row (threads 0..63 = wave 0)
  float c0v = 0.f, c2v = 0.f;
  if (tid < 64) {
    int row = tid;
    float mean = red[128 + row] * (1.f / 256.f);
    float var = red[192 + row] * (1.f / 256.f) - mean * mean;
    float st[4];
    st[0] = fabsf(var - 0.5f);              // surprise
    st[1] = red[64 + row] * (1.f / 256.f);  // excitation
    st[2] = sqrtf(scal[0]);                 // fatigue = |W|_F
    st[3] = 0.5f;                           // coherence
    float z[16];
#pragma unroll
    for (int o = 0; o < 16; ++o) {
      float a = s1b[o];
#pragma unroll
      for (int i = 0; i < 4; ++i) a += s1w[o * 4 + i] * st[i];
      z[o] = a;
    }
    float mu = 0.f;
#pragma unroll
    for (int o = 0; o < 16; ++o) mu += z[o];
    mu *= (1.f / 16.f);
    float vz = 0.f;
#pragma unroll
    for (int o = 0; o < 16; ++o) { float d2 = z[o] - mu; vz += d2 * d2; }
    vz *= (1.f / 16.f);
    float rs = rsqrtf(vz + 1e-5f);
#pragma unroll
    for (int o = 0; o < 16; ++o)
      z[o] = tanhf((z[o] - mu) * rs * lng[o] + lnb[o]);
    float z2[8];
#pragma unroll
    for (int o = 0; o < 8; ++o) {
      float a = s2b[o];
#pragma unroll
      for (int i = 0; i < 16; ++i) a += s2w[o * 16 + i] * z[i];
      z2[o] = fmaxf(a, 0.f);
    }
    float cc[2];
#pragma unroll
    for (int q = 0; q < 2; ++q) {
      int o = q * 2;  // controls[0] and controls[2]
      float a = ab[o];
#pragma unroll
      for (int i = 0; i < 8; ++i) a += aw[o * 8 + i] * z2[i];
      cc[q] = 1.f / (1.f + expf(-a));
    }
    c0v = cc[0]; c2v = cc[1];
    float graw = red[row] + gb[0];
    g_out[r0 + row] = 1.f / (1.f + expf(-graw));
  }
#pragma unroll
  for (int d = 1; d < 64; d <<= 1) {
    c0v += __shfl_xor(c0v, d);
    c2v += __shfl_xor(c2v, d);
  }
  if (tid == 0) {
    atomicAdd(&scal[1], c0v);
    atomicAdd(&scal[2], c2v);
  }
}

// ---------------------------------------------------------------- k_hebb
// r5 structure; NEW: fragment-ordered coalesced parts write.
__global__ __launch_bounds__(512, 2) void k_hebb(
    const float* __restrict__ x, const short* __restrict__ v_in,
    const float* __restrict__ g_sig, const float* __restrict__ scal,
    float* __restrict__ colv2, float* __restrict__ parts,
    float* __restrict__ out0) {
  __shared__ __align__(16) unsigned int ldsT[2 * 256 * 17];  // 34 KiB
  unsigned int* vT = ldsT;
  unsigned int* xT = ldsT + 256 * 17;
  int tid = threadIdx.x;
  int lane = tid & 63, wid = tid >> 6;
  int lr = lane & 15, lg = lane >> 4;
  int wr = wid >> 2, wc = wid & 3;
  size_t n0 = (size_t)blockIdx.x * 1024;
  float gv = scal[2] * (1.f / 262144.f);  // gate_value

  f32x4 acc[8][4] = {};
  float cv2[8] = {0.f, 0.f, 0.f, 0.f, 0.f, 0.f, 0.f, 0.f};
  int np = tid >> 5, ic = tid & 31, i0 = ic * 8;

  for (int nt = 0; nt < 32; ++nt) {
    size_t nr = n0 + nt * 32 + np * 2;
    s16x8 va = *(const s16x8*)(v_in + nr * 256 + i0);
    s16x8 vb = *(const s16x8*)(v_in + (nr + 1) * 256 + i0);
    f32x4 xa0 = *(const f32x4*)(x + nr * 256 + i0);
    f32x4 xa1 = *(const f32x4*)(x + nr * 256 + i0 + 4);
    f32x4 xb0 = *(const f32x4*)(x + (nr + 1) * 256 + i0);
    f32x4 xb1 = *(const f32x4*)(x + (nr + 1) * 256 + i0 + 4);
    float sa = g_sig[nr] * gv, sb = g_sig[nr + 1] * gv;
    f32x4 oa0, oa1, ob0, ob1;
#pragma unroll
    for (int j = 0; j < 4; ++j) {
      float fa = b2f(va[j]), fA = b2f(va[4 + j]);
      float fb = b2f(vb[j]), fB = b2f(vb[4 + j]);
      cv2[j] += fa * fa + fb * fb;
      cv2[4 + j] += fA * fA + fB * fB;
      oa0[j] = clip2(fa * sa); oa1[j] = clip2(fA * sa);
      ob0[j] = clip2(fb * sb); ob1[j] = clip2(fB * sb);
      vT[(i0 + j) * 17 + np] = packu(va[j], vb[j]);
      vT[(i0 + 4 + j) * 17 + np] = packu(va[4 + j], vb[4 + j]);
      xT[(i0 + j) * 17 + np] = packu(f2b(xa0[j]), f2b(xb0[j]));
      xT[(i0 + 4 + j) * 17 + np] = packu(f2b(xa1[j]), f2b(xb1[j]));
    }
    *(f32x4*)(out0 + nr * 256 + i0) = oa0;
    *(f32x4*)(out0 + nr * 256 + i0 + 4) = oa1;
    *(f32x4*)(out0 + (nr + 1) * 256 + i0) = ob0;
    *(f32x4*)(out0 + (nr + 1) * 256 + i0 + 4) = ob1;
    __syncthreads();
    int npb = lg * 4;
    s16x8 bfr[4];
#pragma unroll
    for (int nf = 0; nf < 4; ++nf) {
      int j = wc * 64 + nf * 16 + lr;
      u32x4 q;
      q[0] = xT[j * 17 + npb]; q[1] = xT[j * 17 + npb + 1];
      q[2] = xT[j * 17 + npb + 2]; q[3] = xT[j * 17 + npb + 3];
      bfr[nf] = __builtin_bit_cast(s16x8, q);
    }
#pragma unroll
    for (int mf = 0; mf < 8; ++mf) {
      int i = wr * 128 + mf * 16 + lr;
      u32x4 q;
      q[0] = vT[i * 17 + npb]; q[1] = vT[i * 17 + npb + 1];
      q[2] = vT[i * 17 + npb + 2]; q[3] = vT[i * 17 + npb + 3];
      s16x8 afr = __builtin_bit_cast(s16x8, q);
#pragma unroll
      for (int nf = 0; nf < 4; ++nf)
        acc[mf][nf] = mfma16(afr, bfr[nf], acc[mf][nf]);
    }
    __syncthreads();
  }
  // fragment-ordered parts: each thread's f32x4 contiguous (coalesced 16B)
  float* myp = parts + (size_t)blockIdx.x * 65536;
#pragma unroll
  for (int mf = 0; mf < 8; ++mf)
#pragma unroll
    for (int nf = 0; nf < 4; ++nf)
      *(f32x4*)(myp + (size_t)(((wid * 8 + mf) * 4 + nf) * 64 + lane) * 4) =
          acc[mf][nf];
  __syncthreads();
  float* cred = (float*)ldsT;
  if (tid < 256) cred[tid] = 0.f;
  __syncthreads();
#pragma unroll
  for (int j = 0; j < 8; ++j) atomicAdd(&cred[i0 + j], cv2[j]);
  __syncthreads();
  if (tid < 256) atomicAdd(&colv2[tid], cred[tid]);
}

// ---------------------------------------------------------------- k_mem1
// Reads fragment-ordered parts coalesced. 256 blocks x 64 threads.
__global__ __launch_bounds__(64) void k_mem1(
    const float* __restrict__ parts, const float* __restrict__ colv2,
    const float* __restrict__ sm, float* __restrict__ mem,
    float* __restrict__ scal) {
  int tid = threadIdx.x, bid = blockIdx.x;
  int ibase = bid >> 2;                // i = ibase*4 + e
  int j = (bid & 3) * 64 + tid;        // 0..255
  int wr = ibase >> 5, mf = (ibase >> 2) & 7, lg = ibase & 3;
  int wc = j >> 6, nf = (j >> 4) & 3, lr = j & 15;
  int flat = (((wr * 4 + wc) * 8 + mf) * 4 + nf) * 64 + lg * 16 + lr;
  const float* src = parts + (size_t)flat * 4;
  f32x4 acc = {0.f, 0.f, 0.f, 0.f};
#pragma unroll 4
  for (int p = 0; p < 256; ++p) {
    f32x4 v = *(const f32x4*)(src + (size_t)p * 65536);
    acc += v;
  }
  float mr = scal[1] * (1.f / 262144.f);  // metabolic_rate
  float s = 0.f;
#pragma unroll
  for (int e = 0; e < 4; ++e) {
    int i = ibase * 4 + e;
    float hebb = acc[e] * (1.f / 262144.f);
    float smv = sm[i * 256 + j];
    float forget = colv2[i] * (1.f / 262144.f) * smv;
    float m = smv + tanhf(hebb - forget) * mr * 0.1f;
    mem[i * 256 + j] = m;
    s += m * m;
  }
#pragma unroll
  for (int d = 1; d < 64; d <<= 1) s += __shfl_xor(s, d);
  if (tid == 0) atomicAdd(&scal[3], s);
}

__global__ __launch_bounds__(256) void k_mem2(const float* __restrict__ mem,
                                              const float* __restrict__ scal,
                                              float* __restrict__ out1) {
  int idx = blockIdx.x * 256 + threadIdx.x;
  float scale = 0.5f / fmaxf(sqrtf(scal[3]), 1e-6f);
  out1[idx] = mem[idx] * scale;
}

// ---------------------------------------------------------------- launch
extern "C" void kernel_launch(void* const* d_in, const int* in_sizes, int n_in,
                              void* d_out, int out_size, void* d_ws, size_t ws_size,
                              hipStream_t stream) {
  (void)in_sizes; (void)n_in; (void)out_size; (void)ws_size;
  const float* x   = (const float*)d_in[0];
  const float* Wm  = (const float*)d_in[1];
  const float* Vm  = (const float*)d_in[2];
  const float* gw  = (const float*)d_in[3];
  const float* gb  = (const float*)d_in[4];
  const float* s1w = (const float*)d_in[5];
  const float* s1b = (const float*)d_in[6];
  const float* lng = (const float*)d_in[7];
  const float* lnb = (const float*)d_in[8];
  const float* s2w = (const float*)d_in[9];
  const float* s2b = (const float*)d_in[10];
  const float* aw  = (const float*)d_in[11];
  const float* ab  = (const float*)d_in[12];
  const float* sm  = (const float*)d_in[13];
  float* out0 = (float*)d_out;
  float* out1 = out0 + (size_t)NTOK * 256;

  char* w = (char*)d_ws;
  short* v_ws  = (short*)w;                    // 134217728
  float* g_ws  = (float*)(w + 134217728);      // 1048576
  float* scal  = (float*)(w + 135266304);      // 256
  float* colv2 = (float*)(w + 135266560);      // 1024
  float* mem   = (float*)(w + 135267584);      // 262144
  float* parts = (float*)(w + 135529728);      // 67108864
  short* Vb    = (short*)(w + 202638592);      // 131072
  short* Wb    = (short*)(w + 202769664);      // 131072

  hipMemsetAsync(scal, 0, 1280, stream);       // scal[64] + colv2[256]
  k_prep<<<16, 1024, 0, stream>>>(Vm, Wm, Vb, Wb, scal);
  k_main<<<4096, 512, 0, stream>>>(x, Vb, Wb, gw, gb, s1w, s1b, lng, lnb,
                                   s2w, s2b, aw, ab, v_ws, g_ws, scal);
  k_hebb<<<256, 512, 0, stream>>>(x, v_ws, g_ws, scal, colv2, parts, out0);
  k_mem1<<<256, 64, 0, stream>>>(parts, colv2, sm, mem, scal);
  k_mem2<<<256, 256, 0, stream>>>(mem, scal, out1);
}

// Round 12
// 388.681 us; speedup vs baseline: 1.4064x; 1.0938x over previous
//
#include <hip/hip_runtime.h>
#include <hip/hip_bf16.h>

// MicroContinuumCell — MI355X. f32 I/O; bf16 MFMA internally.
// v12: k_main rebuilt in k_hebb's shape (256 blocks x 1024 rows, 2 barriers
// per 32-row subtile — amortizes the compiler's vmcnt(0)-before-barrier
// drain), fragment-packed B (coalesced 1KB wave reads, no 16-line gathers),
// fragment-ordered ks-XOR LDS for A (conflict-free ds_reads).
// Workspace (~203 MB): offsets in kernel_launch.

#define NTOK 262144

typedef short s16x4 __attribute__((ext_vector_type(4)));
typedef short s16x8 __attribute__((ext_vector_type(8)));
typedef float f32x4 __attribute__((ext_vector_type(4)));
typedef unsigned int u32x4 __attribute__((ext_vector_type(4)));
typedef __bf16 bf16x8 __attribute__((ext_vector_type(8)));

static __device__ __forceinline__ float b2f(short s) {
  unsigned int u = ((unsigned int)(unsigned short)s) << 16;
  return __builtin_bit_cast(float, u);
}
static __device__ __forceinline__ short f2b(float f) {
  __hip_bfloat16 h = __float2bfloat16(f);
  return (short)__builtin_bit_cast(unsigned short, h);
}
static __device__ __forceinline__ float clip2(float f) {
  return fminf(2.f, fmaxf(-2.f, f));
}
static __device__ __forceinline__ unsigned int packu(short lo, short hi) {
  return (unsigned int)(unsigned short)lo | ((unsigned int)(unsigned short)hi << 16);
}
static __device__ __forceinline__ f32x4 mfma16(s16x8 a, s16x8 b, f32x4 c) {
  return __builtin_amdgcn_mfma_f32_16x16x32_bf16(
      __builtin_bit_cast(bf16x8, a), __builtin_bit_cast(bf16x8, b), c, 0, 0, 0);
}

// ---------------------------------------------------------------- k_prep
// Fragment-packs V,W into Vf,Wf: granule (cb,ks,lg,lr) at linear slot
// (cb*8+ks)*64 + lg*16 + lr  (so a wave's B-frag load is 1KB contiguous).
// Also accumulates |W|^2 into scal[0].
__global__ __launch_bounds__(1024) void k_prep(const float* __restrict__ V,
                                               const float* __restrict__ W,
                                               short* __restrict__ Vf,
                                               short* __restrict__ Wf,
                                               float* __restrict__ scal) {
  int t = blockIdx.x * 1024 + threadIdx.x;  // 16384 threads x 4 elems
  int flat = t * 4;
  int col = flat >> 8, k0 = flat & 255;
  f32x4 v4 = *(const f32x4*)(V + flat);
  f32x4 w4 = *(const f32x4*)(W + flat);
  s16x4 vb, wb;
  float s = 0.f;
#pragma unroll
  for (int e = 0; e < 4; ++e) {
    vb[e] = f2b(v4[e]);
    wb[e] = f2b(w4[e]);
    s += w4[e] * w4[e];
  }
  int cb = col >> 4, lrr = col & 15;
  int ks = k0 >> 5, lgg = (k0 >> 3) & 3, j0 = k0 & 7;
  size_t g = (size_t)(((cb * 8 + ks) * 4 + lgg) * 16 + lrr) * 8 + j0;
  *(s16x4*)(Vf + g) = vb;
  *(s16x4*)(Wf + g) = wb;
#pragma unroll
  for (int d = 1; d < 64; d <<= 1) s += __shfl_xor(s, d);
  __shared__ float r[16];
  if ((threadIdx.x & 63) == 0) r[threadIdx.x >> 6] = s;
  __syncthreads();
  if (threadIdx.x == 0) {
    float tt = 0.f;
#pragma unroll
    for (int i = 0; i < 16; ++i) tt += r[i];
    atomicAdd(&scal[0], tt);
  }
}

// ---------------------------------------------------------------- k_main
// 256 blocks x 512 threads; 1024 rows/block; 32 subtiles of 32 rows.
// Per subtile: [copy prev v-tile out] + stage x (frag-ordered LDS, stats)
// -> barrier -> per-wave 32 cols of BOTH products: 8 ks x {2 ds_read A,
// 4 coalesced B loads, 8 MFMA} = 64 MFMA between barriers; clip, gate/|h|
// partials, v -> vs bounce -> barrier. Block end: MLP epilogue.
__global__ __launch_bounds__(512) void k_main(
    const float* __restrict__ x, const short* __restrict__ Vf,
    const short* __restrict__ Wf, const float* __restrict__ gw,
    const float* __restrict__ gb, const float* __restrict__ s1w,
    const float* __restrict__ s1b, const float* __restrict__ lng,
    const float* __restrict__ lnb, const float* __restrict__ s2w,
    const float* __restrict__ s2b, const float* __restrict__ aw,
    const float* __restrict__ ab, short* __restrict__ v_out,
    float* __restrict__ g_out, float* __restrict__ scal) {
  __shared__ __align__(16) short xs[1024 * 8];   // 16 KiB, frag-ordered
  __shared__ __align__(16) short vs[32 * 264];   // 16.5 KiB v bounce
  __shared__ float stat[4096];  // [0)gate [1024)|h| [2048)sx [3072)sxx
  int tid = threadIdx.x;
  int lane = tid & 63, wid = tid >> 6;
  int lr = lane & 15, lg = lane >> 4;
  int np = tid >> 5, ic = tid & 31;  // staging: rows 2np,2np+1; cols ic*8
  int c0 = wid * 32;                 // wave's 32-col slice (both products)
  size_t n0 = (size_t)blockIdx.x * 1024;

#pragma unroll
  for (int q = 0; q < 4; ++q) stat[q * 512 + tid] = 0.f;  // gate & |h|

  float gw0 = gw[c0 + lr], gw1 = gw[c0 + 16 + lr];
  int sks = ic >> 2, slg = ic & 3;  // staging granule coords

  for (int nt = 0; nt < 32; ++nt) {
    int rbase = nt * 32;
    // ---- copy previous subtile's v out (overlaps staging loads)
    if (nt > 0) {
#pragma unroll
      for (int q = 0; q < 2; ++q) {
        int item = q * 512 + tid;
        int row = item >> 5, c8 = item & 31;
        *(s16x8*)(v_out + (n0 + rbase - 32 + row) * 256 + c8 * 8) =
            *(const s16x8*)(vs + row * 264 + c8 * 8);
      }
    }
    // ---- stage x: rows 2np,2np+1, cols ic*8..+7 -> frag-ordered slots
    {
      const float* pa = x + (n0 + rbase + 2 * np) * 256 + ic * 8;
      f32x4 xa0 = *(const f32x4*)pa;
      f32x4 xa1 = *(const f32x4*)(pa + 4);
      f32x4 xb0 = *(const f32x4*)(pa + 256);
      f32x4 xb1 = *(const f32x4*)(pa + 260);
      s16x8 ca, cb;
      float sA = 0.f, qA = 0.f, sB = 0.f, qB = 0.f;
#pragma unroll
      for (int j = 0; j < 4; ++j) {
        sA += xa0[j] + xa1[j];
        qA += xa0[j] * xa0[j] + xa1[j] * xa1[j];
        sB += xb0[j] + xb1[j];
        qB += xb0[j] * xb0[j] + xb1[j] * xb1[j];
        ca[j] = f2b(xa0[j]); ca[4 + j] = f2b(xa1[j]);
        cb[j] = f2b(xb0[j]); cb[4 + j] = f2b(xb1[j]);
      }
      int rowa = 2 * np, rowb = 2 * np + 1;
      int sa = ((rowa >> 4) * 8 + sks) * 64 + ((slg * 16 + (rowa & 15)) ^ sks);
      int sb = ((rowb >> 4) * 8 + sks) * 64 + ((slg * 16 + (rowb & 15)) ^ sks);
      *(s16x8*)(xs + sa * 8) = ca;
      *(s16x8*)(xs + sb * 8) = cb;
#pragma unroll
      for (int d = 1; d < 32; d <<= 1) {
        sA += __shfl_xor(sA, d); qA += __shfl_xor(qA, d);
        sB += __shfl_xor(sB, d); qB += __shfl_xor(qB, d);
      }
      if (ic == 0) {
        stat[2048 + rbase + 2 * np] = sA;
        stat[3072 + rbase + 2 * np] = qA;
        stat[2048 + rbase + 2 * np + 1] = sB;
        stat[3072 + rbase + 2 * np + 1] = qB;
      }
    }
    __syncthreads();
    // ---- compute: 64 MFMAs, no barrier inside
    f32x4 av[2][2] = {}, ah[2][2] = {};
#pragma unroll
    for (int ks = 0; ks < 8; ++ks) {
      s16x8 a0 = *(const s16x8*)(xs + ((ks * 64) + (lane ^ ks)) * 8);
      s16x8 a1 = *(const s16x8*)(xs + (((8 + ks) * 64) + (lane ^ ks)) * 8);
      s16x8 bv0 = *(const s16x8*)(Vf + (size_t)(((wid * 2 + 0) * 8 + ks) * 64 + lane) * 8);
      s16x8 bv1 = *(const s16x8*)(Vf + (size_t)(((wid * 2 + 1) * 8 + ks) * 64 + lane) * 8);
      s16x8 bw0 = *(const s16x8*)(Wf + (size_t)(((wid * 2 + 0) * 8 + ks) * 64 + lane) * 8);
      s16x8 bw1 = *(const s16x8*)(Wf + (size_t)(((wid * 2 + 1) * 8 + ks) * 64 + lane) * 8);
      av[0][0] = mfma16(a0, bv0, av[0][0]);
      av[0][1] = mfma16(a0, bv1, av[0][1]);
      av[1][0] = mfma16(a1, bv0, av[1][0]);
      av[1][1] = mfma16(a1, bv1, av[1][1]);
      ah[0][0] = mfma16(a0, bw0, ah[0][0]);
      ah[0][1] = mfma16(a0, bw1, ah[0][1]);
      ah[1][0] = mfma16(a1, bw0, ah[1][0]);
      ah[1][1] = mfma16(a1, bw1, ah[1][1]);
    }
    // clip v, gate-dot & |h| row-partials, v -> vs bounce
#pragma unroll
    for (int mf = 0; mf < 2; ++mf)
#pragma unroll
      for (int e = 0; e < 4; ++e) {
        float v0 = clip2(av[mf][0][e]), v1 = clip2(av[mf][1][e]);
        av[mf][0][e] = v0; av[mf][1][e] = v1;
        float gd = v0 * gw0 + v1 * gw1;
        float hs = fabsf(ah[mf][0][e]) + fabsf(ah[mf][1][e]);
#pragma unroll
        for (int d = 1; d < 16; d <<= 1) {
          gd += __shfl_xor(gd, d);
          hs += __shfl_xor(hs, d);
        }
        if (lr == 0) {
          int row = rbase + mf * 16 + lg * 4 + e;
          atomicAdd(&stat[row], gd);
          atomicAdd(&stat[1024 + row], hs);
        }
      }
#pragma unroll
    for (int mf = 0; mf < 2; ++mf)
#pragma unroll
      for (int nf = 0; nf < 2; ++nf)
#pragma unroll
        for (int e = 0; e < 4; ++e)
          vs[(mf * 16 + lg * 4 + e) * 264 + c0 + nf * 16 + lr] =
              f2b(av[mf][nf][e]);
    __syncthreads();
  }
  // final subtile's v copy-out
#pragma unroll
  for (int q = 0; q < 2; ++q) {
    int item = q * 512 + tid;
    int row = item >> 5, c8 = item & 31;
    *(s16x8*)(v_out + (n0 + 992 + row) * 256 + c8 * 8) =
        *(const s16x8*)(vs + row * 264 + c8 * 8);
  }

  // ---- deferred per-row MLP: 2 rows/thread
  float c0s = 0.f, c2s = 0.f;
  float wnorm = sqrtf(scal[0]);
#pragma unroll
  for (int rr = 0; rr < 2; ++rr) {
    int r = tid + rr * 512;
    float mean = stat[2048 + r] * (1.f / 256.f);
    float var = stat[3072 + r] * (1.f / 256.f) - mean * mean;
    float st[4];
    st[0] = fabsf(var - 0.5f);
    st[1] = stat[1024 + r] * (1.f / 256.f);
    st[2] = wnorm;
    st[3] = 0.5f;
    float z[16];
#pragma unroll
    for (int o = 0; o < 16; ++o) {
      float a = s1b[o];
#pragma unroll
      for (int i = 0; i < 4; ++i) a += s1w[o * 4 + i] * st[i];
      z[o] = a;
    }
    float mu = 0.f;
#pragma unroll
    for (int o = 0; o < 16; ++o) mu += z[o];
    mu *= (1.f / 16.f);
    float vz = 0.f;
#pragma unroll
    for (int o = 0; o < 16; ++o) { float d2 = z[o] - mu; vz += d2 * d2; }
    vz *= (1.f / 16.f);
    float rs = rsqrtf(vz + 1e-5f);
#pragma unroll
    for (int o = 0; o < 16; ++o)
      z[o] = tanhf((z[o] - mu) * rs * lng[o] + lnb[o]);
    float z2[8];
#pragma unroll
    for (int o = 0; o < 8; ++o) {
      float a = s2b[o];
#pragma unroll
      for (int i = 0; i < 16; ++i) a += s2w[o * 16 + i] * z[i];
      z2[o] = fmaxf(a, 0.f);
    }
#pragma unroll
    for (int q = 0; q < 2; ++q) {
      int o = q * 2;  // controls[0], controls[2]
      float a = ab[o];
#pragma unroll
      for (int i = 0; i < 8; ++i) a += aw[o * 8 + i] * z2[i];
      float cc = 1.f / (1.f + expf(-a));
      if (q == 0) c0s += cc; else c2s += cc;
    }
    g_out[n0 + r] = 1.f / (1.f + expf(-(stat[r] + gb[0])));
  }
#pragma unroll
  for (int d = 1; d < 64; d <<= 1) {
    c0s += __shfl_xor(c0s, d);
    c2s += __shfl_xor(c2s, d);
  }
  if (lane == 0) {
    atomicAdd(&scal[1], c0s);
    atomicAdd(&scal[2], c2s);
  }
}

// ---------------------------------------------------------------- k_hebb
// r11 version: split-K v^T x + fused out0 + colv2; fragment-ordered parts.
__global__ __launch_bounds__(512, 2) void k_hebb(
    const float* __restrict__ x, const short* __restrict__ v_in,
    const float* __restrict__ g_sig, const float* __restrict__ scal,
    float* __restrict__ colv2, float* __restrict__ parts,
    float* __restrict__ out0) {
  __shared__ __align__(16) unsigned int ldsT[2 * 256 * 17];  // 34 KiB
  unsigned int* vT = ldsT;
  unsigned int* xT = ldsT + 256 * 17;
  int tid = threadIdx.x;
  int lane = tid & 63, wid = tid >> 6;
  int lr = lane & 15, lg = lane >> 4;
  int wr = wid >> 2, wc = wid & 3;
  size_t n0 = (size_t)blockIdx.x * 1024;
  float gv = scal[2] * (1.f / 262144.f);  // gate_value

  f32x4 acc[8][4] = {};
  float cv2[8] = {0.f, 0.f, 0.f, 0.f, 0.f, 0.f, 0.f, 0.f};
  int np = tid >> 5, ic = tid & 31, i0 = ic * 8;

  for (int nt = 0; nt < 32; ++nt) {
    size_t nr = n0 + nt * 32 + np * 2;
    s16x8 va = *(const s16x8*)(v_in + nr * 256 + i0);
    s16x8 vb = *(const s16x8*)(v_in + (nr + 1) * 256 + i0);
    f32x4 xa0 = *(const f32x4*)(x + nr * 256 + i0);
    f32x4 xa1 = *(const f32x4*)(x + nr * 256 + i0 + 4);
    f32x4 xb0 = *(const f32x4*)(x + (nr + 1) * 256 + i0);
    f32x4 xb1 = *(const f32x4*)(x + (nr + 1) * 256 + i0 + 4);
    float sa = g_sig[nr] * gv, sb = g_sig[nr + 1] * gv;
    f32x4 oa0, oa1, ob0, ob1;
#pragma unroll
    for (int j = 0; j < 4; ++j) {
      float fa = b2f(va[j]), fA = b2f(va[4 + j]);
      float fb = b2f(vb[j]), fB = b2f(vb[4 + j]);
      cv2[j] += fa * fa + fb * fb;
      cv2[4 + j] += fA * fA + fB * fB;
      oa0[j] = clip2(fa * sa); oa1[j] = clip2(fA * sa);
      ob0[j] = clip2(fb * sb); ob1[j] = clip2(fB * sb);
      vT[(i0 + j) * 17 + np] = packu(va[j], vb[j]);
      vT[(i0 + 4 + j) * 17 + np] = packu(va[4 + j], vb[4 + j]);
      xT[(i0 + j) * 17 + np] = packu(f2b(xa0[j]), f2b(xb0[j]));
      xT[(i0 + 4 + j) * 17 + np] = packu(f2b(xa1[j]), f2b(xb1[j]));
    }
    *(f32x4*)(out0 + nr * 256 + i0) = oa0;
    *(f32x4*)(out0 + nr * 256 + i0 + 4) = oa1;
    *(f32x4*)(out0 + (nr + 1) * 256 + i0) = ob0;
    *(f32x4*)(out0 + (nr + 1) * 256 + i0 + 4) = ob1;
    __syncthreads();
    int npb = lg * 4;
    s16x8 bfr[4];
#pragma unroll
    for (int nf = 0; nf < 4; ++nf) {
      int j = wc * 64 + nf * 16 + lr;
      u32x4 q;
      q[0] = xT[j * 17 + npb]; q[1] = xT[j * 17 + npb + 1];
      q[2] = xT[j * 17 + npb + 2]; q[3] = xT[j * 17 + npb + 3];
      bfr[nf] = __builtin_bit_cast(s16x8, q);
    }
#pragma unroll
    for (int mf = 0; mf < 8; ++mf) {
      int i = wr * 128 + mf * 16 + lr;
      u32x4 q;
      q[0] = vT[i * 17 + npb]; q[1] = vT[i * 17 + npb + 1];
      q[2] = vT[i * 17 + npb + 2]; q[3] = vT[i * 17 + npb + 3];
      s16x8 afr = __builtin_bit_cast(s16x8, q);
#pragma unroll
      for (int nf = 0; nf < 4; ++nf)
        acc[mf][nf] = mfma16(afr, bfr[nf], acc[mf][nf]);
    }
    __syncthreads();
  }
  // fragment-ordered parts: each thread's f32x4 contiguous (coalesced 16B)
  float* myp = parts + (size_t)blockIdx.x * 65536;
#pragma unroll
  for (int mf = 0; mf < 8; ++mf)
#pragma unroll
    for (int nf = 0; nf < 4; ++nf)
      *(f32x4*)(myp + (size_t)(((wid * 8 + mf) * 4 + nf) * 64 + lane) * 4) =
          acc[mf][nf];
  __syncthreads();
  float* cred = (float*)ldsT;
  if (tid < 256) cred[tid] = 0.f;
  __syncthreads();
#pragma unroll
  for (int j = 0; j < 8; ++j) atomicAdd(&cred[i0 + j], cv2[j]);
  __syncthreads();
  if (tid < 256) atomicAdd(&colv2[tid], cred[tid]);
}

// ---------------------------------------------------------------- k_mem1
// 64 blocks x 256 threads; thread q = bid*256+tid owns one f32x4 slot.
__global__ __launch_bounds__(256) void k_mem1(
    const float* __restrict__ parts, const float* __restrict__ colv2,
    const float* __restrict__ sm, float* __restrict__ mem,
    float* __restrict__ scal) {
  int q = blockIdx.x * 256 + threadIdx.x;  // 0..16383
  const float* src = parts + (size_t)q * 4;
  f32x4 acc = {0.f, 0.f, 0.f, 0.f};
#pragma unroll 4
  for (int p = 0; p < 256; ++p) acc += *(const f32x4*)(src + (size_t)p * 65536);
  int lane2 = q & 63, r = q >> 6;
  int lg = lane2 >> 4, lr = lane2 & 15;
  int nf = r & 3, mf = (r >> 2) & 7, wid = r >> 5;
  int wr = wid >> 2, wc = wid & 3;
  int j = wc * 64 + nf * 16 + lr;
  float mr = scal[1] * (1.f / 262144.f);  // metabolic_rate
  float s = 0.f;
#pragma unroll
  for (int e = 0; e < 4; ++e) {
    int i = wr * 128 + mf * 16 + lg * 4 + e;
    float hebb = acc[e] * (1.f / 262144.f);
    float smv = sm[i * 256 + j];
    float forget = colv2[i] * (1.f / 262144.f) * smv;
    float m = smv + tanhf(hebb - forget) * mr * 0.1f;
    mem[i * 256 + j] = m;
    s += m * m;
  }
#pragma unroll
  for (int d = 1; d < 64; d <<= 1) s += __shfl_xor(s, d);
  __shared__ float r4[4];
  if ((threadIdx.x & 63) == 0) r4[threadIdx.x >> 6] = s;
  __syncthreads();
  if (threadIdx.x == 0) atomicAdd(&scal[3], r4[0] + r4[1] + r4[2] + r4[3]);
}

__global__ __launch_bounds__(256) void k_mem2(const float* __restrict__ mem,
                                              const float* __restrict__ scal,
                                              float* __restrict__ out1) {
  int idx = blockIdx.x * 256 + threadIdx.x;
  float scale = 0.5f / fmaxf(sqrtf(scal[3]), 1e-6f);
  out1[idx] = mem[idx] * scale;
}

// ---------------------------------------------------------------- launch
extern "C" void kernel_launch(void* const* d_in, const int* in_sizes, int n_in,
                              void* d_out, int out_size, void* d_ws, size_t ws_size,
                              hipStream_t stream) {
  (void)in_sizes; (void)n_in; (void)out_size; (void)ws_size;
  const float* x   = (const float*)d_in[0];
  const float* Wm  = (const float*)d_in[1];
  const float* Vm  = (const float*)d_in[2];
  const float* gw  = (const float*)d_in[3];
  const float* gb  = (const float*)d_in[4];
  const float* s1w = (const float*)d_in[5];
  const float* s1b = (const float*)d_in[6];
  const float* lng = (const float*)d_in[7];
  const float* lnb = (const float*)d_in[8];
  const float* s2w = (const float*)d_in[9];
  const float* s2b = (const float*)d_in[10];
  const float* aw  = (const float*)d_in[11];
  const float* ab  = (const float*)d_in[12];
  const float* sm  = (const float*)d_in[13];
  float* out0 = (float*)d_out;
  float* out1 = out0 + (size_t)NTOK * 256;

  char* w = (char*)d_ws;
  short* v_ws  = (short*)w;                    // 134217728
  float* g_ws  = (float*)(w + 134217728);      // 1048576
  float* scal  = (float*)(w + 135266304);      // 256
  float* colv2 = (float*)(w + 135266560);      // 1024
  float* mem   = (float*)(w + 135267584);      // 262144
  float* parts = (float*)(w + 135529728);      // 67108864
  short* Vf    = (short*)(w + 202638592);      // 131072 (frag-packed)
  short* Wf    = (short*)(w + 202769664);      // 131072 (frag-packed)

  hipMemsetAsync(scal, 0, 1280, stream);       // scal[64] + colv2[256]
  k_prep<<<16, 1024, 0, stream>>>(Vm, Wm, Vf, Wf, scal);
  k_main<<<256, 512, 0, stream>>>(x, Vf, Wf, gw, gb, s1w, s1b, lng, lnb,
                                  s2w, s2b, aw, ab, v_ws, g_ws, scal);
  k_hebb<<<256, 512, 0, stream>>>(x, v_ws, g_ws, scal, colv2, parts, out0);
  k_mem1<<<64, 256, 0, stream>>>(parts, colv2, sm, mem, scal);
  k_mem2<<<256, 256, 0, stream>>>(mem, scal, out1);
}